// Round 3
// baseline (596.690 us; speedup 1.0000x reference)
//
#include <hip/hip_runtime.h>

#define N_TOK 2048
#define DIM   1024
#define NE    8
#define HID   2048
#define A_SHARED 4096
#define OUT_HID (N_TOK * DIM)

typedef float v4f __attribute__((ext_vector_type(4)));
typedef short v8s __attribute__((ext_vector_type(8)));

// ---- workspace layout (bytes) ----
#define OFF_XBF   0ull
#define OFF_H     4194304ull
#define OFF_GW    29360128ull
#define OFF_UW    67108864ull
#define OFF_DW    104857600ull
#define OFF_TOK   142606336ull
#define OFF_WL    (OFF_TOK + 24576ull)
#define OFF_IDX   (OFF_WL + 24576ull)
#define OFF_TW    (OFF_IDX + 16384ull)
#define OFF_STATS (OFF_TW + 16384ull)

struct Stats {
  int counts[NE];
  int fill[NE];
  int offs[NE + 2];
  float z2;
  float psum[NE];
};

__device__ __forceinline__ unsigned short f2bf(float f) {
  union { float f; unsigned u; } v; v.f = f;
  unsigned r = v.u + 0x7FFFu + ((v.u >> 16) & 1u);
  return (unsigned short)(r >> 16);
}
__device__ __forceinline__ unsigned pack2bf(float a, float b) {
  return (unsigned)f2bf(a) | ((unsigned)f2bf(b) << 16);
}

__device__ __forceinline__ void async_lds16(const void* g, void* l) {
  __builtin_amdgcn_global_load_lds(
      (const __attribute__((address_space(1))) void*)g,
      (__attribute__((address_space(3))) void*)l, 16, 0, 0);
}

// ---- cast x to bf16 ----
__global__ __launch_bounds__(256) void cast_x_kernel(const float* __restrict__ x,
                                                     unsigned short* __restrict__ xbf) {
  int i = blockIdx.x * 256 + threadIdx.x;
  float4 v = ((const float4*)x)[i];
  uint2 o;
  o.x = pack2bf(v.x, v.y);
  o.y = pack2bf(v.z, v.w);
  ((uint2*)xbf)[i] = o;
}

// ---- cast all weights to bf16; shared expert becomes expert 8 ----
#define VR 4718592
#define VE 4194304
__global__ __launch_bounds__(256) void cast_w_kernel(
    const float* __restrict__ g, const float* __restrict__ u, const float* __restrict__ dn,
    const float* __restrict__ shg, const float* __restrict__ shu, const float* __restrict__ shd,
    unsigned short* __restrict__ outw) {
  unsigned i = blockIdx.x * 256 + threadIdx.x;
  unsigned r = i / VR;
  unsigned j = i - r * VR;
  const float* eb = (r == 0) ? g : (r == 1) ? u : dn;
  const float* sb = (r == 0) ? shg : (r == 1) ? shu : shd;
  const float* src = (j < VE) ? eb + 4ull * j : sb + 4ull * (j - VE);
  float4 v = *(const float4*)src;
  uint2 o;
  o.x = pack2bf(v.x, v.y);
  o.y = pack2bf(v.z, v.w);
  ((uint2*)outw)[i] = o;
}

// ---- router ----
__global__ __launch_bounds__(256) void router_kernel(
    const float* __restrict__ x, const float* __restrict__ rw, const float* __restrict__ rb,
    int* __restrict__ idxbuf, float* __restrict__ twbuf, Stats* __restrict__ st) {
  int lane = threadIdx.x & 63;
  int wv = threadIdx.x >> 6;
  int n = blockIdx.x * 4 + wv;

  float acc[NE];
#pragma unroll
  for (int e = 0; e < NE; ++e) acc[e] = 0.f;

  const float4* x4 = (const float4*)(x + (size_t)n * DIM);
#pragma unroll
  for (int q = 0; q < 4; ++q) {
    float4 xv = x4[q * 64 + lane];
#pragma unroll
    for (int e = 0; e < NE; ++e) {
      const float4* w4 = (const float4*)(rw + (size_t)e * DIM);
      float4 wvv = w4[q * 64 + lane];
      acc[e] += xv.x * wvv.x + xv.y * wvv.y + xv.z * wvv.z + xv.w * wvv.w;
    }
  }
#pragma unroll
  for (int off = 32; off; off >>= 1) {
#pragma unroll
    for (int e = 0; e < NE; ++e) acc[e] += __shfl_xor(acc[e], off);
  }

  float mx = acc[0];
#pragma unroll
  for (int e = 1; e < NE; ++e) mx = fmaxf(mx, acc[e]);
  float pr[NE];
  float es = 0.f;
#pragma unroll
  for (int e = 0; e < NE; ++e) { pr[e] = __expf(acc[e] - mx); es += pr[e]; }
  float inv = 1.f / es;
#pragma unroll
  for (int e = 0; e < NE; ++e) pr[e] *= inv;
  float z = mx + __logf(es);

  float b0 = -1e30f; int i0 = 0;
#pragma unroll
  for (int e = 0; e < NE; ++e) {
    float bb = acc[e] + rb[e];
    if (bb > b0) { b0 = bb; i0 = e; }
  }
  float b1 = -1e30f; int i1 = 0;
#pragma unroll
  for (int e = 0; e < NE; ++e) {
    if (e == i0) continue;
    float bb = acc[e] + rb[e];
    if (bb > b1) { b1 = bb; i1 = e; }
  }
  float l0 = acc[i0], l1 = acc[i1];
  float m2 = fmaxf(l0, l1);
  float e0 = __expf(l0 - m2), e1 = __expf(l1 - m2);
  float den = 1.f / (e0 + e1);
  float w0 = e0 * den, w1 = e1 * den;

  __shared__ float redp[4][9];
  __shared__ int redc[4][8];
  if (lane == 0) {
    idxbuf[n * 2] = i0; idxbuf[n * 2 + 1] = i1;
    twbuf[n * 2] = w0;  twbuf[n * 2 + 1] = w1;
#pragma unroll
    for (int e = 0; e < NE; ++e) redp[wv][e] = pr[e];
    redp[wv][8] = z * z;
#pragma unroll
    for (int e = 0; e < NE; ++e) redc[wv][e] = (e == i0) + (e == i1);
  }
  __syncthreads();
  int t = threadIdx.x;
  if (t < 9) {
    float s = redp[0][t] + redp[1][t] + redp[2][t] + redp[3][t];
    if (t < 8) atomicAdd(&st->psum[t], s);
    else       atomicAdd(&st->z2, s);
  } else if (t >= 16 && t < 24) {
    int e = t - 16;
    atomicAdd(&st->counts[e], redc[0][e] + redc[1][e] + redc[2][e] + redc[3][e]);
  }
}

// ---- scan ----
__global__ void scan_kernel(Stats* __restrict__ st, float* __restrict__ out) {
  if (threadIdx.x == 0 && blockIdx.x == 0) {
    int o = 0;
#pragma unroll
    for (int e = 0; e < NE; ++e) { st->offs[e] = o; o += st->counts[e]; }
    st->offs[NE] = o;
    st->offs[NE + 1] = o + N_TOK;
    float zl = st->z2 / (float)N_TOK * 1e-4f;
    float lb = 0.f;
#pragma unroll
    for (int e = 0; e < NE; ++e)
      lb += (st->psum[e] / (float)N_TOK) * ((float)st->counts[e] / (float)N_TOK);
    lb *= (float)NE;
    out[OUT_HID + 0] = 0.f;
    out[OUT_HID + 1] = zl;
    out[OUT_HID + 2] = lb;
  }
}

// ---- scatter ----
__global__ __launch_bounds__(256) void scatter_kernel(
    const int* __restrict__ idxbuf, const float* __restrict__ twbuf,
    Stats* __restrict__ st, int* __restrict__ tok, float* __restrict__ wl) {
  int n = blockIdx.x * 256 + threadIdx.x;
#pragma unroll
  for (int k = 0; k < 2; ++k) {
    int e = idxbuf[n * 2 + k];
    int pos = st->offs[e] + atomicAdd(&st->fill[e], 1);
    tok[pos] = n;
    wl[pos] = twbuf[n * 2 + k];
  }
  tok[A_SHARED + n] = n;
  wl[A_SHARED + n] = 1.f;
}

// ============================================================
// LDS tile layout (per 128x32 bf16 tile): 64 super-rows (2 rows
// = 128 B = 8 granules of 16 B). Granule g of super-row R holds
// super-chunk s = g ^ (R&7): row 2R+(s>>2), k-chunk s&3.
// Fragment reads hit all 8 bank-groups with exactly 2 lanes each.
// Staging: slab of 16 rows (8 super-rows, aligned) per wave-issue;
// lane l stages (row 2*(l>>3)+(((l&7)^(l>>3))>>2), chunk ((l&7)^(l>>3))&3)
// and LDS receives it at granule l.  Read offset for (row r, chunk kc):
// elem = (r>>1)*64 + (((r&1)*4+kc) ^ ((r>>1)&7))*8.
// ============================================================

// ---- gate+up grouped GEMM, 128x128 tile, double-buffered async staging ----
__global__ __launch_bounds__(256, 2) void gateup_kernel(
    const unsigned short* __restrict__ gwbf, const unsigned short* __restrict__ uwbf,
    const unsigned short* __restrict__ xbf, const int* __restrict__ tok,
    const Stats* __restrict__ st, unsigned short* __restrict__ hbuf) {
  int e = blockIdx.z;
  int seg0 = st->offs[e];
  int cnt = st->offs[e + 1] - seg0;
  int m0 = blockIdx.x * 128;
  if (m0 >= cnt) return;
  int n0 = blockIdx.y * 128;

  __shared__ alignas(16) unsigned short As[2][128 * 32];
  __shared__ alignas(16) unsigned short Bg[2][128 * 32];
  __shared__ alignas(16) unsigned short Bu[2][128 * 32];

  int tid = threadIdx.x, l = tid & 63, w = tid >> 6;
  int wr = w >> 1, wc = w & 1;

  // staging lane geometry (swizzled)
  int sj = l >> 3;                 // super-row within slab
  int ss = (l & 7) ^ sj;           // super-chunk
  int grow = 2 * sj + (ss >> 2);   // row within 16-row slab
  int gch = ss & 3;                // k-chunk

  const unsigned short* ap[2];
  const unsigned short* gp[2];
  const unsigned short* up[2];
#pragma unroll
  for (int q = 0; q < 2; ++q) {
    int row = (w * 2 + q) * 16 + grow;
    int ar = m0 + row; if (ar > cnt - 1) ar = cnt - 1;
    ap[q] = xbf + (size_t)tok[seg0 + ar] * DIM + gch * 8;
    size_t wb = (size_t)e * HID * DIM + (size_t)(n0 + row) * DIM + gch * 8;
    gp[q] = gwbf + wb;
    up[q] = uwbf + wb;
  }

  // per-lane constant fragment read offset (elements)
  int lh = (l & 15) >> 1;
  int lofs = lh * 64 + ((((l & 1) * 4 + (l >> 4)) ^ lh) * 8);

  v4f accg[4][4], accu[4][4];
#pragma unroll
  for (int mi = 0; mi < 4; ++mi)
#pragma unroll
    for (int ni = 0; ni < 4; ++ni) {
      accg[mi][ni] = (v4f){0.f, 0.f, 0.f, 0.f};
      accu[mi][ni] = (v4f){0.f, 0.f, 0.f, 0.f};
    }

  // prologue stage into buffer 0
#pragma unroll
  for (int q = 0; q < 2; ++q) {
    async_lds16(ap[q], &As[0][(w * 2 + q) * 512]);
    async_lds16(gp[q], &Bg[0][(w * 2 + q) * 512]);
    async_lds16(up[q], &Bu[0][(w * 2 + q) * 512]);
  }

  int pb = 0;
  for (int k0 = 0; k0 < DIM; k0 += 32, pb ^= 1) {
    __syncthreads();   // drains buffer-pb loads (in flight during prev compute)
    if (k0 + 32 < DIM) {
      int nb = pb ^ 1;
      int kn = k0 + 32;
#pragma unroll
      for (int q = 0; q < 2; ++q) {
        async_lds16(ap[q] + kn, &As[nb][(w * 2 + q) * 512]);
        async_lds16(gp[q] + kn, &Bg[nb][(w * 2 + q) * 512]);
        async_lds16(up[q] + kn, &Bu[nb][(w * 2 + q) * 512]);
      }
    }

    v8s af[4], bgf[4], buf_[4];
#pragma unroll
    for (int mi = 0; mi < 4; ++mi)
      af[mi] = *(const v8s*)&As[pb][(wr * 32 + mi * 8) * 64 + lofs];
#pragma unroll
    for (int ni = 0; ni < 4; ++ni) {
      bgf[ni]  = *(const v8s*)&Bg[pb][(wc * 32 + ni * 8) * 64 + lofs];
      buf_[ni] = *(const v8s*)&Bu[pb][(wc * 32 + ni * 8) * 64 + lofs];
    }
#pragma unroll
    for (int mi = 0; mi < 4; ++mi)
#pragma unroll
      for (int ni = 0; ni < 4; ++ni) {
        accg[mi][ni] = __builtin_amdgcn_mfma_f32_16x16x32_bf16(af[mi], bgf[ni], accg[mi][ni], 0, 0, 0);
        accu[mi][ni] = __builtin_amdgcn_mfma_f32_16x16x32_bf16(af[mi], buf_[ni], accu[mi][ni], 0, 0, 0);
      }
  }

  int col = l & 15, rq = (l >> 4) * 4;
#pragma unroll
  for (int mi = 0; mi < 4; ++mi) {
#pragma unroll
    for (int rr = 0; rr < 4; ++rr) {
      int rl = wr * 64 + mi * 16 + rq + rr;
      if (m0 + rl < cnt) {
        size_t rowb = (size_t)(seg0 + m0 + rl) * HID + n0 + wc * 64;
#pragma unroll
        for (int ni = 0; ni < 4; ++ni) {
          float g = accg[mi][ni][rr], u = accu[mi][ni][rr];
          hbuf[rowb + ni * 16 + col] = f2bf(g * u / (1.f + __expf(-g)));
        }
      }
    }
  }
}

// ---- down grouped GEMM, 128x128 tile, double-buffered ----
__global__ __launch_bounds__(256, 2) void down_kernel(
    const unsigned short* __restrict__ dwbf, const unsigned short* __restrict__ hbuf,
    const int* __restrict__ tok, const float* __restrict__ wl,
    const Stats* __restrict__ st, float* __restrict__ out) {
  int e = blockIdx.z;
  int seg0 = st->offs[e];
  int cnt = st->offs[e + 1] - seg0;
  int m0 = blockIdx.x * 128;
  if (m0 >= cnt) return;
  int n0 = blockIdx.y * 128;

  __shared__ alignas(16) unsigned short As[2][128 * 32];
  __shared__ alignas(16) unsigned short Bs[2][128 * 32];

  int tid = threadIdx.x, l = tid & 63, w = tid >> 6;
  int wr = w >> 1, wc = w & 1;

  int sj = l >> 3;
  int ss = (l & 7) ^ sj;
  int grow = 2 * sj + (ss >> 2);
  int gch = ss & 3;

  const unsigned short* ap[2];
  const unsigned short* bp[2];
#pragma unroll
  for (int q = 0; q < 2; ++q) {
    int row = (w * 2 + q) * 16 + grow;
    int ar = m0 + row; if (ar > cnt - 1) ar = cnt - 1;
    ap[q] = hbuf + (size_t)(seg0 + ar) * HID + gch * 8;
    bp[q] = dwbf + (size_t)e * DIM * HID + (size_t)(n0 + row) * HID + gch * 8;
  }

  int lh = (l & 15) >> 1;
  int lofs = lh * 64 + ((((l & 1) * 4 + (l >> 4)) ^ lh) * 8);

  v4f acc[4][4];
#pragma unroll
  for (int mi = 0; mi < 4; ++mi)
#pragma unroll
    for (int ni = 0; ni < 4; ++ni) acc[mi][ni] = (v4f){0.f, 0.f, 0.f, 0.f};

#pragma unroll
  for (int q = 0; q < 2; ++q) {
    async_lds16(ap[q], &As[0][(w * 2 + q) * 512]);
    async_lds16(bp[q], &Bs[0][(w * 2 + q) * 512]);
  }

  int pb = 0;
  for (int k0 = 0; k0 < HID; k0 += 32, pb ^= 1) {
    __syncthreads();
    if (k0 + 32 < HID) {
      int nb = pb ^ 1;
      int kn = k0 + 32;
#pragma unroll
      for (int q = 0; q < 2; ++q) {
        async_lds16(ap[q] + kn, &As[nb][(w * 2 + q) * 512]);
        async_lds16(bp[q] + kn, &Bs[nb][(w * 2 + q) * 512]);
      }
    }

    v8s af[4], bf[4];
#pragma unroll
    for (int mi = 0; mi < 4; ++mi)
      af[mi] = *(const v8s*)&As[pb][(wr * 32 + mi * 8) * 64 + lofs];
#pragma unroll
    for (int ni = 0; ni < 4; ++ni)
      bf[ni] = *(const v8s*)&Bs[pb][(wc * 32 + ni * 8) * 64 + lofs];
#pragma unroll
    for (int mi = 0; mi < 4; ++mi)
#pragma unroll
      for (int ni = 0; ni < 4; ++ni)
        acc[mi][ni] = __builtin_amdgcn_mfma_f32_16x16x32_bf16(af[mi], bf[ni], acc[mi][ni], 0, 0, 0);
  }

  int col = l & 15, rq = (l >> 4) * 4;
#pragma unroll
  for (int mi = 0; mi < 4; ++mi) {
#pragma unroll
    for (int rr = 0; rr < 4; ++rr) {
      int rl = wr * 64 + mi * 16 + rq + rr;
      if (m0 + rl < cnt) {
        int t = tok[seg0 + m0 + rl];
        float wgt = wl[seg0 + m0 + rl];
        float* ob = out + (size_t)t * DIM + n0 + wc * 64;
#pragma unroll
        for (int ni = 0; ni < 4; ++ni)
          atomicAdd(ob + ni * 16 + col, acc[mi][ni][rr] * wgt);
      }
    }
  }
}

extern "C" void kernel_launch(void* const* d_in, const int* in_sizes, int n_in,
                              void* d_out, int out_size, void* d_ws, size_t ws_size,
                              hipStream_t stream) {
  const float* x   = (const float*)d_in[0];
  const float* rw  = (const float*)d_in[1];
  const float* rb  = (const float*)d_in[2];
  const float* gw  = (const float*)d_in[3];
  const float* uw  = (const float*)d_in[4];
  const float* dw  = (const float*)d_in[5];
  const float* shg = (const float*)d_in[6];
  const float* shu = (const float*)d_in[7];
  const float* shd = (const float*)d_in[8];
  float* out = (float*)d_out;
  char* ws = (char*)d_ws;

  unsigned short* xbf  = (unsigned short*)(ws + OFF_XBF);
  unsigned short* hbuf = (unsigned short*)(ws + OFF_H);
  unsigned short* gwbf = (unsigned short*)(ws + OFF_GW);
  unsigned short* uwbf = (unsigned short*)(ws + OFF_UW);
  unsigned short* dwbf = (unsigned short*)(ws + OFF_DW);
  int*   tok  = (int*)(ws + OFF_TOK);
  float* wl   = (float*)(ws + OFF_WL);
  int*   idxb = (int*)(ws + OFF_IDX);
  float* twb  = (float*)(ws + OFF_TW);
  Stats* st   = (Stats*)(ws + OFF_STATS);

  hipMemsetAsync(d_out, 0, (size_t)out_size * sizeof(float), stream);
  hipMemsetAsync(st, 0, sizeof(Stats), stream);

  cast_x_kernel<<<2048, 256, 0, stream>>>(x, xbf);
  cast_w_kernel<<<55296, 256, 0, stream>>>(gw, uw, dw, shg, shu, shd, gwbf);
  router_kernel<<<512, 256, 0, stream>>>(x, rw, rb, idxb, twb, st);
  scan_kernel<<<1, 64, 0, stream>>>(st, out);
  scatter_kernel<<<8, 256, 0, stream>>>(idxb, twb, st, tok, wl);
  gateup_kernel<<<dim3(16, 16, 9), 256, 0, stream>>>(gwbf, uwbf, xbf, tok, st, hbuf);
  down_kernel<<<dim3(16, 8, 9), 256, 0, stream>>>(dwbf, hbuf, tok, wl, st, out);
}

// Round 4
// 417.351 us; speedup vs baseline: 1.4297x; 1.4297x over previous
//
#include <hip/hip_runtime.h>

#define N_TOK 2048
#define DIM   1024
#define NE    8
#define HID   2048
#define A_SHARED 4096
#define OUT_HID (N_TOK * DIM)

typedef float v4f __attribute__((ext_vector_type(4)));
typedef short v8s __attribute__((ext_vector_type(8)));

// ---- workspace layout (bytes) ----
#define OFF_XBF   0ull
#define OFF_H     4194304ull
#define OFF_GW    29360128ull
#define OFF_UW    67108864ull
#define OFF_DW    104857600ull
#define OFF_TOK   142606336ull
#define OFF_WL    (OFF_TOK + 24576ull)
#define OFF_IDX   (OFF_WL + 24576ull)
#define OFF_TW    (OFF_IDX + 16384ull)
#define OFF_STATS (OFF_TW + 16384ull)

struct Stats {
  int counts[NE];
  int fill[NE];
  int offs[NE + 2];
  float z2;
  float psum[NE];
};

__device__ __forceinline__ unsigned short f2bf(float f) {
  union { float f; unsigned u; } v; v.f = f;
  unsigned r = v.u + 0x7FFFu + ((v.u >> 16) & 1u);
  return (unsigned short)(r >> 16);
}
__device__ __forceinline__ unsigned pack2bf(float a, float b) {
  return (unsigned)f2bf(a) | ((unsigned)f2bf(b) << 16);
}

__device__ __forceinline__ void async_lds16(const void* g, void* l) {
  __builtin_amdgcn_global_load_lds(
      (const __attribute__((address_space(1))) void*)g,
      (__attribute__((address_space(3))) void*)l, 16, 0, 0);
}

// ---- cast x to bf16 ----
__global__ __launch_bounds__(256) void cast_x_kernel(const float* __restrict__ x,
                                                     unsigned short* __restrict__ xbf) {
  int i = blockIdx.x * 256 + threadIdx.x;
  float4 v = ((const float4*)x)[i];
  uint2 o;
  o.x = pack2bf(v.x, v.y);
  o.y = pack2bf(v.z, v.w);
  ((uint2*)xbf)[i] = o;
}

// ---- cast all weights to bf16; shared expert becomes expert 8 ----
#define VR 4718592
#define VE 4194304
__global__ __launch_bounds__(256) void cast_w_kernel(
    const float* __restrict__ g, const float* __restrict__ u, const float* __restrict__ dn,
    const float* __restrict__ shg, const float* __restrict__ shu, const float* __restrict__ shd,
    unsigned short* __restrict__ outw) {
  unsigned i = blockIdx.x * 256 + threadIdx.x;
  unsigned r = i / VR;
  unsigned j = i - r * VR;
  const float* eb = (r == 0) ? g : (r == 1) ? u : dn;
  const float* sb = (r == 0) ? shg : (r == 1) ? shu : shd;
  const float* src = (j < VE) ? eb + 4ull * j : sb + 4ull * (j - VE);
  float4 v = *(const float4*)src;
  uint2 o;
  o.x = pack2bf(v.x, v.y);
  o.y = pack2bf(v.z, v.w);
  ((uint2*)outw)[i] = o;
}

// ---- router ----
__global__ __launch_bounds__(256) void router_kernel(
    const float* __restrict__ x, const float* __restrict__ rw, const float* __restrict__ rb,
    int* __restrict__ idxbuf, float* __restrict__ twbuf, Stats* __restrict__ st) {
  int lane = threadIdx.x & 63;
  int wv = threadIdx.x >> 6;
  int n = blockIdx.x * 4 + wv;

  float acc[NE];
#pragma unroll
  for (int e = 0; e < NE; ++e) acc[e] = 0.f;

  const float4* x4 = (const float4*)(x + (size_t)n * DIM);
#pragma unroll
  for (int q = 0; q < 4; ++q) {
    float4 xv = x4[q * 64 + lane];
#pragma unroll
    for (int e = 0; e < NE; ++e) {
      const float4* w4 = (const float4*)(rw + (size_t)e * DIM);
      float4 wvv = w4[q * 64 + lane];
      acc[e] += xv.x * wvv.x + xv.y * wvv.y + xv.z * wvv.z + xv.w * wvv.w;
    }
  }
#pragma unroll
  for (int off = 32; off; off >>= 1) {
#pragma unroll
    for (int e = 0; e < NE; ++e) acc[e] += __shfl_xor(acc[e], off);
  }

  float mx = acc[0];
#pragma unroll
  for (int e = 1; e < NE; ++e) mx = fmaxf(mx, acc[e]);
  float pr[NE];
  float es = 0.f;
#pragma unroll
  for (int e = 0; e < NE; ++e) { pr[e] = __expf(acc[e] - mx); es += pr[e]; }
  float inv = 1.f / es;
#pragma unroll
  for (int e = 0; e < NE; ++e) pr[e] *= inv;
  float z = mx + __logf(es);

  float b0 = -1e30f; int i0 = 0;
#pragma unroll
  for (int e = 0; e < NE; ++e) {
    float bb = acc[e] + rb[e];
    if (bb > b0) { b0 = bb; i0 = e; }
  }
  float b1 = -1e30f; int i1 = 0;
#pragma unroll
  for (int e = 0; e < NE; ++e) {
    if (e == i0) continue;
    float bb = acc[e] + rb[e];
    if (bb > b1) { b1 = bb; i1 = e; }
  }
  float l0 = acc[i0], l1 = acc[i1];
  float m2 = fmaxf(l0, l1);
  float e0 = __expf(l0 - m2), e1 = __expf(l1 - m2);
  float den = 1.f / (e0 + e1);
  float w0 = e0 * den, w1 = e1 * den;

  __shared__ float redp[4][9];
  __shared__ int redc[4][8];
  if (lane == 0) {
    idxbuf[n * 2] = i0; idxbuf[n * 2 + 1] = i1;
    twbuf[n * 2] = w0;  twbuf[n * 2 + 1] = w1;
#pragma unroll
    for (int e = 0; e < NE; ++e) redp[wv][e] = pr[e];
    redp[wv][8] = z * z;
#pragma unroll
    for (int e = 0; e < NE; ++e) redc[wv][e] = (e == i0) + (e == i1);
  }
  __syncthreads();
  int t = threadIdx.x;
  if (t < 9) {
    float s = redp[0][t] + redp[1][t] + redp[2][t] + redp[3][t];
    if (t < 8) atomicAdd(&st->psum[t], s);
    else       atomicAdd(&st->z2, s);
  } else if (t >= 16 && t < 24) {
    int e = t - 16;
    atomicAdd(&st->counts[e], redc[0][e] + redc[1][e] + redc[2][e] + redc[3][e]);
  }
}

// ---- scan ----
__global__ void scan_kernel(Stats* __restrict__ st, float* __restrict__ out) {
  if (threadIdx.x == 0 && blockIdx.x == 0) {
    int o = 0;
#pragma unroll
    for (int e = 0; e < NE; ++e) { st->offs[e] = o; o += st->counts[e]; }
    st->offs[NE] = o;
    st->offs[NE + 1] = o + N_TOK;
    float zl = st->z2 / (float)N_TOK * 1e-4f;
    float lb = 0.f;
#pragma unroll
    for (int e = 0; e < NE; ++e)
      lb += (st->psum[e] / (float)N_TOK) * ((float)st->counts[e] / (float)N_TOK);
    lb *= (float)NE;
    out[OUT_HID + 0] = 0.f;
    out[OUT_HID + 1] = zl;
    out[OUT_HID + 2] = lb;
  }
}

// ---- scatter ----
__global__ __launch_bounds__(256) void scatter_kernel(
    const int* __restrict__ idxbuf, const float* __restrict__ twbuf,
    Stats* __restrict__ st, int* __restrict__ tok, float* __restrict__ wl) {
  int n = blockIdx.x * 256 + threadIdx.x;
#pragma unroll
  for (int k = 0; k < 2; ++k) {
    int e = idxbuf[n * 2 + k];
    int pos = st->offs[e] + atomicAdd(&st->fill[e], 1);
    tok[pos] = n;
    wl[pos] = twbuf[n * 2 + k];
  }
  tok[A_SHARED + n] = n;
  wl[A_SHARED + n] = 1.f;
}

// ============================================================
// LDS swizzle (per 128x32 bf16 tile): 64 super-rows of 128 B
// (8 granules of 16 B); granule g of super-row R holds
// super-chunk g^(R&7). Fragment ds_read_b128s hit all 8
// bank-groups, 2 lanes each (free). Verified: 0 conflicts (r3).
//
// Grid note: blockIdx.x = n-tile (dense), blockIdx.y = m-tile
// (sparse: only y*128<cnt work). With x fastest in the linear
// workgroup id and round-robin id%8 XCD assignment, working
// blocks spread over all 8 XCDs. With roles swapped (r2/r3),
// routed-expert blocks all had id%8<4 -> XCDs 0-3 only, half
// the chip idle.
// ============================================================

// ---- gate+up grouped GEMM, 128x128 tile, double-buffered ----
__global__ __launch_bounds__(256, 2) void gateup_kernel(
    const unsigned short* __restrict__ gwbf, const unsigned short* __restrict__ uwbf,
    const unsigned short* __restrict__ xbf, const int* __restrict__ tok,
    const Stats* __restrict__ st, unsigned short* __restrict__ hbuf) {
  int e = blockIdx.z;
  int seg0 = st->offs[e];
  int cnt = st->offs[e + 1] - seg0;
  int m0 = blockIdx.y * 128;          // m-tile on Y (sparse)
  if (m0 >= cnt) return;
  int n0 = blockIdx.x * 128;          // n-tile on X (dense)

  __shared__ alignas(16) unsigned short As[2][128 * 32];
  __shared__ alignas(16) unsigned short Bg[2][128 * 32];
  __shared__ alignas(16) unsigned short Bu[2][128 * 32];

  int tid = threadIdx.x, l = tid & 63, w = tid >> 6;
  int wr = w >> 1, wc = w & 1;

  int sj = l >> 3;
  int ss = (l & 7) ^ sj;
  int grow = 2 * sj + (ss >> 2);
  int gch = ss & 3;

  const unsigned short* ap[2];
  const unsigned short* gp[2];
  const unsigned short* up[2];
#pragma unroll
  for (int q = 0; q < 2; ++q) {
    int row = (w * 2 + q) * 16 + grow;
    int ar = m0 + row; if (ar > cnt - 1) ar = cnt - 1;
    ap[q] = xbf + (size_t)tok[seg0 + ar] * DIM + gch * 8;
    size_t wb = (size_t)e * HID * DIM + (size_t)(n0 + row) * DIM + gch * 8;
    gp[q] = gwbf + wb;
    up[q] = uwbf + wb;
  }

  int lh = (l & 15) >> 1;
  int lofs = lh * 64 + ((((l & 1) * 4 + (l >> 4)) ^ lh) * 8);

  v4f accg[4][4], accu[4][4];
#pragma unroll
  for (int mi = 0; mi < 4; ++mi)
#pragma unroll
    for (int ni = 0; ni < 4; ++ni) {
      accg[mi][ni] = (v4f){0.f, 0.f, 0.f, 0.f};
      accu[mi][ni] = (v4f){0.f, 0.f, 0.f, 0.f};
    }

#pragma unroll
  for (int q = 0; q < 2; ++q) {
    async_lds16(ap[q], &As[0][(w * 2 + q) * 512]);
    async_lds16(gp[q], &Bg[0][(w * 2 + q) * 512]);
    async_lds16(up[q], &Bu[0][(w * 2 + q) * 512]);
  }

  int pb = 0;
  for (int k0 = 0; k0 < DIM; k0 += 32, pb ^= 1) {
    __syncthreads();

    // read this iteration's fragments first...
    v8s af[4], bgf[4], buf_[4];
#pragma unroll
    for (int mi = 0; mi < 4; ++mi)
      af[mi] = *(const v8s*)&As[pb][(wr * 32 + mi * 8) * 64 + lofs];
#pragma unroll
    for (int ni = 0; ni < 4; ++ni) {
      bgf[ni]  = *(const v8s*)&Bg[pb][(wc * 32 + ni * 8) * 64 + lofs];
      buf_[ni] = *(const v8s*)&Bu[pb][(wc * 32 + ni * 8) * 64 + lofs];
    }

    // ...then issue next tile's async loads (fly during the MFMA phase)
    if (k0 + 32 < DIM) {
      int nb = pb ^ 1;
      int kn = k0 + 32;
#pragma unroll
      for (int q = 0; q < 2; ++q) {
        async_lds16(ap[q] + kn, &As[nb][(w * 2 + q) * 512]);
        async_lds16(gp[q] + kn, &Bg[nb][(w * 2 + q) * 512]);
        async_lds16(up[q] + kn, &Bu[nb][(w * 2 + q) * 512]);
      }
    }

#pragma unroll
    for (int mi = 0; mi < 4; ++mi)
#pragma unroll
      for (int ni = 0; ni < 4; ++ni) {
        accg[mi][ni] = __builtin_amdgcn_mfma_f32_16x16x32_bf16(af[mi], bgf[ni], accg[mi][ni], 0, 0, 0);
        accu[mi][ni] = __builtin_amdgcn_mfma_f32_16x16x32_bf16(af[mi], buf_[ni], accu[mi][ni], 0, 0, 0);
      }
  }

  int col = l & 15, rq = (l >> 4) * 4;
#pragma unroll
  for (int mi = 0; mi < 4; ++mi) {
#pragma unroll
    for (int rr = 0; rr < 4; ++rr) {
      int rl = wr * 64 + mi * 16 + rq + rr;
      if (m0 + rl < cnt) {
        size_t rowb = (size_t)(seg0 + m0 + rl) * HID + n0 + wc * 64;
#pragma unroll
        for (int ni = 0; ni < 4; ++ni) {
          float g = accg[mi][ni][rr], u = accu[mi][ni][rr];
          hbuf[rowb + ni * 16 + col] = f2bf(g * u / (1.f + __expf(-g)));
        }
      }
    }
  }
}

// ---- down grouped GEMM, 128x128 tile, double-buffered ----
__global__ __launch_bounds__(256, 2) void down_kernel(
    const unsigned short* __restrict__ dwbf, const unsigned short* __restrict__ hbuf,
    const int* __restrict__ tok, const float* __restrict__ wl,
    const Stats* __restrict__ st, float* __restrict__ out) {
  int e = blockIdx.z;
  int seg0 = st->offs[e];
  int cnt = st->offs[e + 1] - seg0;
  int m0 = blockIdx.y * 128;          // m-tile on Y (sparse)
  if (m0 >= cnt) return;
  int n0 = blockIdx.x * 128;          // n-tile on X (dense, over DIM)

  __shared__ alignas(16) unsigned short As[2][128 * 32];
  __shared__ alignas(16) unsigned short Bs[2][128 * 32];

  int tid = threadIdx.x, l = tid & 63, w = tid >> 6;
  int wr = w >> 1, wc = w & 1;

  int sj = l >> 3;
  int ss = (l & 7) ^ sj;
  int grow = 2 * sj + (ss >> 2);
  int gch = ss & 3;

  const unsigned short* ap[2];
  const unsigned short* bp[2];
#pragma unroll
  for (int q = 0; q < 2; ++q) {
    int row = (w * 2 + q) * 16 + grow;
    int ar = m0 + row; if (ar > cnt - 1) ar = cnt - 1;
    ap[q] = hbuf + (size_t)(seg0 + ar) * HID + gch * 8;
    bp[q] = dwbf + (size_t)e * DIM * HID + (size_t)(n0 + row) * HID + gch * 8;
  }

  int lh = (l & 15) >> 1;
  int lofs = lh * 64 + ((((l & 1) * 4 + (l >> 4)) ^ lh) * 8);

  v4f acc[4][4];
#pragma unroll
  for (int mi = 0; mi < 4; ++mi)
#pragma unroll
    for (int ni = 0; ni < 4; ++ni) acc[mi][ni] = (v4f){0.f, 0.f, 0.f, 0.f};

#pragma unroll
  for (int q = 0; q < 2; ++q) {
    async_lds16(ap[q], &As[0][(w * 2 + q) * 512]);
    async_lds16(bp[q], &Bs[0][(w * 2 + q) * 512]);
  }

  int pb = 0;
  for (int k0 = 0; k0 < HID; k0 += 32, pb ^= 1) {
    __syncthreads();

    v8s af[4], bf[4];
#pragma unroll
    for (int mi = 0; mi < 4; ++mi)
      af[mi] = *(const v8s*)&As[pb][(wr * 32 + mi * 8) * 64 + lofs];
#pragma unroll
    for (int ni = 0; ni < 4; ++ni)
      bf[ni] = *(const v8s*)&Bs[pb][(wc * 32 + ni * 8) * 64 + lofs];

    if (k0 + 32 < HID) {
      int nb = pb ^ 1;
      int kn = k0 + 32;
#pragma unroll
      for (int q = 0; q < 2; ++q) {
        async_lds16(ap[q] + kn, &As[nb][(w * 2 + q) * 512]);
        async_lds16(bp[q] + kn, &Bs[nb][(w * 2 + q) * 512]);
      }
    }

#pragma unroll
    for (int mi = 0; mi < 4; ++mi)
#pragma unroll
      for (int ni = 0; ni < 4; ++ni)
        acc[mi][ni] = __builtin_amdgcn_mfma_f32_16x16x32_bf16(af[mi], bf[ni], acc[mi][ni], 0, 0, 0);
  }

  int col = l & 15, rq = (l >> 4) * 4;
#pragma unroll
  for (int mi = 0; mi < 4; ++mi) {
#pragma unroll
    for (int rr = 0; rr < 4; ++rr) {
      int rl = wr * 64 + mi * 16 + rq + rr;
      if (m0 + rl < cnt) {
        int t = tok[seg0 + m0 + rl];
        float wgt = wl[seg0 + m0 + rl];
        float* ob = out + (size_t)t * DIM + n0 + wc * 64;
#pragma unroll
        for (int ni = 0; ni < 4; ++ni)
          atomicAdd(ob + ni * 16 + col, acc[mi][ni][rr] * wgt);
      }
    }
  }
}

extern "C" void kernel_launch(void* const* d_in, const int* in_sizes, int n_in,
                              void* d_out, int out_size, void* d_ws, size_t ws_size,
                              hipStream_t stream) {
  const float* x   = (const float*)d_in[0];
  const float* rw  = (const float*)d_in[1];
  const float* rb  = (const float*)d_in[2];
  const float* gw  = (const float*)d_in[3];
  const float* uw  = (const float*)d_in[4];
  const float* dw  = (const float*)d_in[5];
  const float* shg = (const float*)d_in[6];
  const float* shu = (const float*)d_in[7];
  const float* shd = (const float*)d_in[8];
  float* out = (float*)d_out;
  char* ws = (char*)d_ws;

  unsigned short* xbf  = (unsigned short*)(ws + OFF_XBF);
  unsigned short* hbuf = (unsigned short*)(ws + OFF_H);
  unsigned short* gwbf = (unsigned short*)(ws + OFF_GW);
  unsigned short* uwbf = (unsigned short*)(ws + OFF_UW);
  unsigned short* dwbf = (unsigned short*)(ws + OFF_DW);
  int*   tok  = (int*)(ws + OFF_TOK);
  float* wl   = (float*)(ws + OFF_WL);
  int*   idxb = (int*)(ws + OFF_IDX);
  float* twb  = (float*)(ws + OFF_TW);
  Stats* st   = (Stats*)(ws + OFF_STATS);

  hipMemsetAsync(d_out, 0, (size_t)out_size * sizeof(float), stream);
  hipMemsetAsync(st, 0, sizeof(Stats), stream);

  cast_x_kernel<<<2048, 256, 0, stream>>>(x, xbf);
  cast_w_kernel<<<55296, 256, 0, stream>>>(gw, uw, dw, shg, shu, shd, gwbf);
  router_kernel<<<512, 256, 0, stream>>>(x, rw, rb, idxb, twb, st);
  scan_kernel<<<1, 64, 0, stream>>>(st, out);
  scatter_kernel<<<8, 256, 0, stream>>>(idxb, twb, st, tok, wl);
  gateup_kernel<<<dim3(16, 16, 9), 256, 0, stream>>>(gwbf, uwbf, xbf, tok, st, hbuf);
  down_kernel<<<dim3(8, 16, 9), 256, 0, stream>>>(dwbf, hbuf, tok, wl, st, out);
}